// Round 4
// baseline (1726.865 us; speedup 1.0000x reference)
//
#include <hip/hip_runtime.h>

#define T_SEQ 2048
#define HID   5120
#define QLR   1536
#define KVLR  512
#define NOPE  128
#define ROPE_D 64
#define VDIM  128
#define NH    32
#define QKD   192

constexpr float SCALE   = 0.07216878364870323f; // 192^-0.5
constexpr float EPS_F   = 1e-6f;
constexpr float LN10000 = 9.210340371976184f;

typedef __bf16 bf16x8 __attribute__((ext_vector_type(8)));
typedef float  f32x4  __attribute__((ext_vector_type(4)));

__device__ __forceinline__ unsigned short f2bf(float f) {
  union { float f; unsigned u; } v; v.f = f;
  unsigned u = v.u + 0x7fffu + ((v.u >> 16) & 1u);
  return (unsigned short)(u >> 16);
}
__device__ __forceinline__ float bf2f(unsigned short b) {
  union { unsigned u; float f; } v; v.u = ((unsigned)b) << 16;
  return v.f;
}

// async global->LDS, 16B per lane; LDS dest = wave-uniform base + lane*16
__device__ __forceinline__ void glds16(const unsigned short* g, unsigned short* l) {
  __builtin_amdgcn_global_load_lds((const __attribute__((address_space(1))) void*)g,
                                   (__attribute__((address_space(3))) void*)l, 16, 0, 0);
}

// ---------------- elementwise f32 -> bf16 ----------------
__global__ void conv_f2b(const float* __restrict__ in, unsigned short* __restrict__ out, long n) {
  long i = ((long)blockIdx.x * blockDim.x + threadIdx.x) * 4;
  if (i >= n) return;
  float4 v = *(const float4*)(in + i);
  uint2 o;
  o.x = (unsigned)f2bf(v.x) | ((unsigned)f2bf(v.y) << 16);
  o.y = (unsigned)f2bf(v.z) | ((unsigned)f2bf(v.w) << 16);
  *(uint2*)(out + i) = o;
}

// ---------------- transpose f32 (RxC) -> bf16 (CxR), batched ----------------
__global__ void transpose_f2b(const float* __restrict__ in, unsigned short* __restrict__ out,
                              int R, int C, long inB, long outB) {
  __shared__ float tile[32][33];
  const float* inp = in + (long)blockIdx.z * inB;
  unsigned short* outp = out + (long)blockIdx.z * outB;
  int c0 = blockIdx.x * 32, r0 = blockIdx.y * 32;
  int x = threadIdx.x, y = threadIdx.y; // (32,8)
#pragma unroll
  for (int yy = 0; yy < 32; yy += 8)
    tile[y + yy][x] = inp[(long)(r0 + y + yy) * C + c0 + x];
  __syncthreads();
#pragma unroll
  for (int yy = 0; yy < 32; yy += 8)
    outp[(long)(c0 + y + yy) * R + r0 + x] = f2bf(tile[x][y + yy]);
}

// ---------------- rmsnorm rows (f32 in, bf16 out) ----------------
__global__ void rmsnorm_rows(const float* __restrict__ in, const float* __restrict__ w,
                             unsigned short* __restrict__ out, int C) {
  int t = blockIdx.x, tid = threadIdx.x;
  __shared__ float sred[4];
  const float* row = in + (long)t * C;
  float ss = 0.f;
  for (int i = tid; i < C; i += 256) { float v = row[i]; ss += v * v; }
#pragma unroll
  for (int o = 32; o; o >>= 1) ss += __shfl_xor(ss, o);
  if ((tid & 63) == 0) sred[tid >> 6] = ss;
  __syncthreads();
  ss = sred[0] + sred[1] + sred[2] + sred[3];
  float rinv = rsqrtf(ss / (float)C + EPS_F);
  for (int i = tid; i < C; i += 256)
    out[(long)t * C + i] = f2bf(row[i] * rinv * w[i]);
}

// ---------------- kv latent: rmsnorm(512)->k_input & v_t; rope on k_pe ----------------
__global__ void norm_rope_k(const float* __restrict__ latent, const float* __restrict__ w,
                            unsigned short* __restrict__ k_input, unsigned short* __restrict__ v_t) {
  int t = blockIdx.x, tid = threadIdx.x;
  __shared__ float sred[4];
  const float* row = latent + (long)t * 576;
  float ss = 0.f;
  for (int i = tid; i < 512; i += 256) { float v = row[i]; ss += v * v; }
#pragma unroll
  for (int o = 32; o; o >>= 1) ss += __shfl_xor(ss, o);
  if ((tid & 63) == 0) sred[tid >> 6] = ss;
  __syncthreads();
  ss = sred[0] + sred[1] + sred[2] + sred[3];
  float rinv = rsqrtf(ss * (1.f / 512.f) + EPS_F);
  for (int i = tid; i < 512; i += 256) {
    unsigned short b = f2bf(row[i] * rinv * w[i]);
    k_input[(long)t * 576 + i] = b;
    v_t[(long)i * T_SEQ + t] = b;  // V^T for PV MFMA B-frags
  }
  if (tid < 32) {
    float fr = (float)t * expf(-((float)(2 * tid) / 64.f) * LN10000);
    float c = cosf(fr), s = sinf(fr);
    float x1 = row[512 + 2 * tid], x2 = row[512 + 2 * tid + 1];
    k_input[(long)t * 576 + 512 + 2 * tid]     = f2bf(x1 * c - x2 * s);
    k_input[(long)t * 576 + 512 + 2 * tid + 1] = f2bf(x2 * c + x1 * s);
  }
}

// ---------------- rope on q_pe: q (T, H*192) -> q_input[h][t][512..576] ----------------
__global__ void rope_q(const unsigned short* __restrict__ q, unsigned short* __restrict__ q_input) {
  int idx = blockIdx.x * 256 + threadIdx.x; // t*NH*32 + h*32 + i
  int i = idx & 31, h = (idx >> 5) & 31, t = idx >> 10;
  float fr = (float)t * expf(-((float)(2 * i) / 64.f) * LN10000);
  float c = cosf(fr), s = sinf(fr);
  const unsigned short* qp = q + (long)t * (NH * QKD) + h * QKD + NOPE + 2 * i;
  float x1 = bf2f(qp[0]), x2 = bf2f(qp[1]);
  unsigned short* op = q_input + ((long)h * T_SEQ + t) * 576 + 512 + 2 * i;
  op[0] = f2bf(x1 * c - x2 * s);
  op[1] = f2bf(x2 * c + x1 * s);
}

// ---------------- GEMM: C[M,N] = A[M,K] @ Bt[N,K]^T (bf16 in, f32 acc) ----------------
template <bool OUT_BF16>
__global__ __launch_bounds__(256, 2)
void gemm_bt(const unsigned short* __restrict__ A, const unsigned short* __restrict__ Bt,
             void* __restrict__ Cv, int N, int K,
             long lda, long ldb, long ldc, long bA, long bB, long bC) {
  __shared__ __align__(16) unsigned short sA[128 * 64];
  __shared__ __align__(16) unsigned short sB[128 * 64];
  const int b = blockIdx.z;
  const unsigned short* Ap = A + (long)b * bA;
  const unsigned short* Bp = Bt + (long)b * bB;
  const int m0 = blockIdx.x * 128, n0 = blockIdx.y * 128;
  const int tid = threadIdx.x, lane = tid & 63, w = tid >> 6;
  const int wr = w >> 1, wc = w & 1, lo = lane & 15, hi = lane >> 4;
  f32x4 acc[4][4];
#pragma unroll
  for (int i = 0; i < 4; i++)
#pragma unroll
    for (int j = 0; j < 4; j++) acc[i][j] = (f32x4){0.f, 0.f, 0.f, 0.f};
  const int r0 = tid >> 3, cc = tid & 7;
  for (int k0 = 0; k0 < K; k0 += 64) {
    __syncthreads();
#pragma unroll
    for (int i = 0; i < 4; i++) {
      glds16(Ap + (long)(m0 + i * 32 + r0) * lda + k0 + cc * 8, sA + i * 2048 + w * 512);
      glds16(Bp + (long)(n0 + i * 32 + r0) * ldb + k0 + cc * 8, sB + i * 2048 + w * 512);
    }
    __syncthreads();
#pragma unroll
    for (int s = 0; s < 2; s++) {
      bf16x8 af[4], bfr[4];
#pragma unroll
      for (int mt = 0; mt < 4; mt++)
        af[mt] = *(const bf16x8*)(sA + (wr * 64 + mt * 16 + lo) * 64 + s * 32 + hi * 8);
#pragma unroll
      for (int nt = 0; nt < 4; nt++)
        bfr[nt] = *(const bf16x8*)(sB + (wc * 64 + nt * 16 + lo) * 64 + s * 32 + hi * 8);
#pragma unroll
      for (int mt = 0; mt < 4; mt++)
#pragma unroll
        for (int nt = 0; nt < 4; nt++)
          acc[mt][nt] = __builtin_amdgcn_mfma_f32_16x16x32_bf16(af[mt], bfr[nt], acc[mt][nt], 0, 0, 0);
    }
  }
#pragma unroll
  for (int mt = 0; mt < 4; mt++)
#pragma unroll
    for (int nt = 0; nt < 4; nt++) {
      int col = n0 + wc * 64 + nt * 16 + lo;
      if (col < N) {
#pragma unroll
        for (int r = 0; r < 4; r++) {
          long row = m0 + wr * 64 + mt * 16 + hi * 4 + r;
          float v = acc[mt][nt][r];
          if constexpr (OUT_BF16)
            ((unsigned short*)Cv)[(long)b * bC + row * ldc + col] = f2bf(v);
          else
            ((float*)Cv)[(long)b * bC + row * ldc + col] = v;
        }
      }
    }
}

// ---------------- flash attention v8: unified 4-buffer pool -> 32 KB LDS, 4 blocks/CU ----
// v7 protocol (counted vmcnt, stage-ahead D=2, uniform 8 KB chunks) kept verbatim.
// Insight: K and V chunks form ONE interleaved sequence of 17 chunks/tile, so the
// B>=D+2 liveness bound needs only a SINGLE pool of 4 buffers (32 KB), not 4+4
// (64 KB). Chunk c staged at slot c-2 (pre-barrier_s) conflicts with chunk c-4,
// whose compute finished before barrier_{s-1} which all waves passed -> safe.
// 17 % 4 == 1, so the pool base rotates by 1 buffer per tile: block-uniform kb0
// (SGPR), buffer = (kb0 + c) & 3. vmcnt table unchanged: steady WB(4), tail
// WB(2)/WB(0). LDS 64->32 KB doubles occupancy: 4 blocks/CU (16 waves, 50%).
// __launch_bounds__(256,4) pins VGPR at <=128 (currently exactly 128).
__global__ __launch_bounds__(256, 4)
void flash_attn(const unsigned short* __restrict__ q_input,
                const unsigned short* __restrict__ k_input,
                const unsigned short* __restrict__ v_t,
                unsigned short* __restrict__ ctx_out) {
  __shared__ __align__(16) unsigned short sKV[4 * 64 * 64];  // 32 KB pool, 4 bufs x 8 KB
  const int h = blockIdx.x;
  const int i0 = (31 - blockIdx.y) * 64;  // biggest blocks dispatch first
  const int tid = threadIdx.x;
  const int lane = tid & 63, w = tid >> 6;
  const int lo = lane & 15, hi = lane >> 4;
  const int qrow = i0 + w * 16 + lo;

  bf16x8 qf[18];
  {
    const unsigned short* qr = q_input + ((long)h * T_SEQ + qrow) * 576;
#pragma unroll
    for (int i = 0; i < 18; i++) qf[i] = *(const bf16x8*)(qr + i * 32 + hi * 8);
  }
  // settle qf loads HERE (one vmcnt wait outside the loop) so no qf-related
  // vmcnt waits appear inside the pipeline.
#pragma unroll
  for (int i = 0; i < 18; i++) asm volatile("" : "+v"(qf[i]));

  float l_r = 0.f;
  f32x4 of[32];
#pragma unroll
  for (int o = 0; o < 32; o++) of[o] = (f32x4){0.f, 0.f, 0.f, 0.f};

  // staging lane constants (element offsets). Chunk = 64 rows x 64 cols bf16;
  // 16B-unit u = w*128 + i*64 + lane; row = u>>3, slot = (u ^ (u>>3)) & 7.
  int kOff[2], vOff[2];
#pragma unroll
  for (int i = 0; i < 2; i++) {
    int u = w * 128 + i * 64 + lane;
    int sl = (u ^ (u >> 3)) & 7;        // inverse-swizzled source slot
    kOff[i] = (u >> 3) * 576 + sl * 8;  // K: row = key (stride 576)
    vOff[i] = (u >> 3) * T_SEQ + sl * 8;// V^T: row = vd (stride T_SEQ)
  }
  // read-side swizzle: 16B-group ((ks*4+hi)^(lo&7)), in elements
  const int sw[2] = { ((0 + hi) ^ (lo & 7)) * 8, ((4 + hi) ^ (lo & 7)) * 8 };
  int kb0 = 0;  // buffer index of this tile's chunk 0 (uniform, SGPR)

#define BUF(ci) ((kb0 + (ci)) & 3)
#define STAGE_K(c, ci, base)                                                  \
  {                                                                           \
    unsigned short* d_ = sKV + BUF(ci) * 4096 + w * 1024;                     \
    _Pragma("unroll")                                                         \
    for (int i_ = 0; i_ < 2; i_++)                                            \
      glds16(k_input + (base) + kOff[i_] + (c) * 64, d_ + i_ * 512);          \
  }
#define STAGE_V(ch, jk)                                                       \
  {                                                                           \
    unsigned short* d_ = sKV + BUF(9 + (ch)) * 4096 + w * 1024;               \
    _Pragma("unroll")                                                         \
    for (int i_ = 0; i_ < 2; i_++)                                            \
      glds16(v_t + (long)(ch) * 64 * T_SEQ + vOff[i_] + (jk), d_ + i_ * 512); \
  }
#define WB(N)                                                                 \
  __builtin_amdgcn_sched_barrier(0);                                          \
  asm volatile("s_waitcnt vmcnt(" #N ")" ::: "memory");                       \
  __builtin_amdgcn_s_barrier();                                               \
  __builtin_amdgcn_sched_barrier(0);
#define COMPUTE_K(c)                                                          \
  {                                                                           \
    const unsigned short* kb_ = sKV + BUF(c) * 4096 + lo * 64;                \
    _Pragma("unroll")                                                         \
    for (int ks_ = 0; ks_ < 2; ks_++)                                         \
      _Pragma("unroll")                                                       \
      for (int nt_ = 0; nt_ < 4; nt_++) {                                     \
        bf16x8 a_ = *(const bf16x8*)(kb_ + nt_ * 1024 + sw[ks_]);             \
        sacc[nt_] = __builtin_amdgcn_mfma_f32_16x16x32_bf16(                  \
            a_, qf[2 * (c) + ks_], sacc[nt_], 0, 0, 0);                       \
      }                                                                       \
  }
#define COMPUTE_V(ch)                                                         \
  {                                                                           \
    const unsigned short* vb_ = sKV + BUF(9 + (ch)) * 4096 + lo * 64;         \
    _Pragma("unroll")                                                         \
    for (int kk_ = 0; kk_ < 2; kk_++)                                         \
      _Pragma("unroll")                                                       \
      for (int ot_ = 0; ot_ < 4; ot_++) {                                     \
        bf16x8 b_ = *(const bf16x8*)(vb_ + ot_ * 1024 + sw[kk_]);             \
        of[(ch) * 4 + ot_] = __builtin_amdgcn_mfma_f32_16x16x32_bf16(         \
            pa[kk_], b_, of[(ch) * 4 + ot_], 0, 0, 0);                        \
      }                                                                       \
  }

  // prologue: chunks 0,1 of first tile (outstanding = 4)
  STAGE_K(0, 0, 0); STAGE_K(1, 1, 0);

  for (int j0 = 0; j0 <= i0; j0 += 64) {
    const long kcur = (long)j0 * 576;
    const long knxt = kcur + 64 * 576;
    const bool more = (j0 < i0);
    f32x4 sacc[4];
#pragma unroll
    for (int nt = 0; nt < 4; nt++) sacc[nt] = (f32x4){0.f, 0.f, 0.f, 0.f};

    // ---- K slots 0..8 (chunks 0..8) ----
    STAGE_K(2, 2, kcur); WB(4); COMPUTE_K(0);
    STAGE_K(3, 3, kcur); WB(4); COMPUTE_K(1);
    STAGE_K(4, 4, kcur); WB(4); COMPUTE_K(2);
    STAGE_K(5, 5, kcur); WB(4); COMPUTE_K(3);
    STAGE_K(6, 6, kcur); WB(4); COMPUTE_K(4);
    STAGE_K(7, 7, kcur); WB(4); COMPUTE_K(5);
    STAGE_K(8, 8, kcur); WB(4); COMPUTE_K(6);
    STAGE_V(0, j0);      WB(4); COMPUTE_K(7);
    STAGE_V(1, j0);      WB(4); COMPUTE_K(8);

    // ---- softmax (no max-tracking; stats are per-lane) ----
    const bool diag = (j0 == i0);
    int D2[4][2];
    float psum = 0.f;
#pragma unroll
    for (int nt = 0; nt < 4; nt++) {
      float pv[4];
#pragma unroll
      for (int r = 0; r < 4; r++) {
        float e = __expf(sacc[nt][r] * SCALE);
        if (diag && (j0 + nt * 16 + hi * 4 + r) > qrow) e = 0.f;
        pv[r] = e;
        psum += e;
      }
      D2[nt][0] = (int)f2bf(pv[0]) | ((int)f2bf(pv[1]) << 16);
      D2[nt][1] = (int)f2bf(pv[2]) | ((int)f2bf(pv[3]) << 16);
    }
    psum += __shfl_xor(psum, 16);
    psum += __shfl_xor(psum, 32);
    l_r += psum;
    // ---- P -> PV A-frags in-register (two bpermute rounds + select) ----
    bf16x8 pa[2];
    {
      const int s0 = lo + 32 * (hi & 1);
#pragma unroll
      for (int kk = 0; kk < 2; kk++) {
        int d[4];
#pragma unroll
        for (int dd = 0; dd < 2; dd++) {
          int t0 = __shfl(D2[2 * kk][dd], s0);
          int t1 = __shfl(D2[2 * kk + 1][dd], s0);
          d[dd] = (hi >> 1) ? t1 : t0;
          int t2 = __shfl(D2[2 * kk][dd], s0 + 16);
          int t3 = __shfl(D2[2 * kk + 1][dd], s0 + 16);
          d[2 + dd] = (hi >> 1) ? t3 : t2;
        }
        int4 di = {d[0], d[1], d[2], d[3]};
        pa[kk] = *(bf16x8*)&di;
      }
    }
    // ---- V slots 9..16 (chunks 9..16) ----
    STAGE_V(2, j0); WB(4); COMPUTE_V(0);
    STAGE_V(3, j0); WB(4); COMPUTE_V(1);
    STAGE_V(4, j0); WB(4); COMPUTE_V(2);
    STAGE_V(5, j0); WB(4); COMPUTE_V(3);
    STAGE_V(6, j0); WB(4); COMPUTE_V(4);
    STAGE_V(7, j0); WB(4); COMPUTE_V(5);
    if (more) { STAGE_K(0, 17, knxt); WB(4); } else { WB(2); }
    COMPUTE_V(6);
    if (more) { STAGE_K(1, 18, knxt); WB(4); } else { WB(0); }
    COMPUTE_V(7);
    kb0 = (kb0 + 1) & 3;  // 17 chunks % 4 buffers == 1
  }
#undef BUF
#undef STAGE_K
#undef STAGE_V
#undef WB
#undef COMPUTE_K
#undef COMPUTE_V

  // ---- epilogue ----
  float linv[4];
#pragma unroll
  for (int r = 0; r < 4; r++) linv[r] = 1.f / __shfl(l_r, hi * 4 + r);
#pragma unroll
  for (int o = 0; o < 32; o++) {
    int vd = o * 16 + lo;
#pragma unroll
    for (int r = 0; r < 4; r++) {
      long row = (long)h * T_SEQ + i0 + w * 16 + hi * 4 + r;
      ctx_out[row * 576 + vd] = f2bf(of[o][r] * linv[r]);
    }
  }
}

// ---------------- host orchestration ----------------
extern "C" void kernel_launch(void* const* d_in, const int* in_sizes, int n_in,
                              void* d_out, int out_size, void* d_ws, size_t ws_size,
                              hipStream_t stream) {
  (void)in_sizes; (void)n_in; (void)out_size; (void)ws_size;
  const float* hs    = (const float*)d_in[0];
  const float* wqa   = (const float*)d_in[2];
  const float* qlnw  = (const float*)d_in[3];
  const float* wqb   = (const float*)d_in[4];
  const float* wkva  = (const float*)d_in[5];
  const float* kvlnw = (const float*)d_in[6];
  const float* wkc   = (const float*)d_in[7];
  const float* wvc   = (const float*)d_in[8];
  const float* wo    = (const float*)d_in[9];
  float* out = (float*)d_out;

  char* base = (char*)d_ws;
  size_t off = 0;
  auto alloc = [&](size_t bytes) {
    char* r = base + off;
    off += (bytes + 255) & ~(size_t)255;
    return r;
  };
  unsigned short* hs_b  = (unsigned short*)alloc((size_t)T_SEQ * HID * 2);
  unsigned short* wqaT  = (unsigned short*)alloc((size_t)QLR * HID * 2);
  unsigned short* wqbT  = (unsigned short*)alloc((size_t)NH * QKD * QLR * 2);
  unsigned short* wkvaT = (unsigned short*)alloc((size_t)640 * HID * 2);  // 576 padded to 640
  unsigned short* wkcT  = (unsigned short*)alloc((size_t)NH * 512 * 128 * 2);
  unsigned short* wvcT  = (unsigned short*)alloc((size_t)NH * 128 * 512 * 2);
  float*          q_a   = (float*)alloc((size_t)T_SEQ * QLR * 4);
  unsigned short* q_a_n = (unsigned short*)alloc((size_t)T_SEQ * QLR * 2);
  unsigned short* qbuf  = (unsigned short*)alloc((size_t)T_SEQ * NH * QKD * 2);
  float*          latent= (float*)alloc((size_t)T_SEQ * 576 * 4);
  unsigned short* k_inp = (unsigned short*)alloc((size_t)T_SEQ * 576 * 2);
  unsigned short* v_t   = (unsigned short*)alloc((size_t)512 * T_SEQ * 2);
  unsigned short* q_inp = (unsigned short*)alloc((size_t)NH * T_SEQ * 576 * 2);
  unsigned short* woT   = (unsigned short*)base;  // over hs_b+wqaT+wqbT (dead by then)
  unsigned short* attn  = qbuf;                   // over qbuf (dead by then)

  dim3 tb(32, 8);
  conv_f2b<<<(T_SEQ * HID) / 1024, 256, 0, stream>>>(hs, hs_b, (long)T_SEQ * HID);
  transpose_f2b<<<dim3(QLR / 32, HID / 32, 1), tb, 0, stream>>>(wqa, wqaT, HID, QLR, 0, 0);
  transpose_f2b<<<dim3(576 / 32, HID / 32, 1), tb, 0, stream>>>(wkva, wkvaT, HID, 576, 0, 0);
  gemm_bt<false><<<dim3(T_SEQ / 128, QLR / 128, 1), 256, 0, stream>>>(
      hs_b, wqaT, q_a, QLR, HID, HID, HID, QLR, 0, 0, 0);
  gemm_bt<false><<<dim3(T_SEQ / 128, 5, 1), 256, 0, stream>>>(
      hs_b, wkvaT, latent, 576, HID, HID, HID, 576, 0, 0, 0);
  rmsnorm_rows<<<T_SEQ, 256, 0, stream>>>(q_a, qlnw, q_a_n, QLR);
  norm_rope_k<<<T_SEQ, 256, 0, stream>>>(latent, kvlnw, k_inp, v_t);
  transpose_f2b<<<dim3((NH * QKD) / 32, QLR / 32, 1), tb, 0, stream>>>(wqb, wqbT, QLR, NH * QKD, 0, 0);
  gemm_bt<true><<<dim3(T_SEQ / 128, (NH * QKD) / 128, 1), 256, 0, stream>>>(
      q_a_n, wqbT, qbuf, NH * QKD, QLR, QLR, QLR, NH * QKD, 0, 0, 0);
  transpose_f2b<<<dim3(512 / 32, 128 / 32, NH), tb, 0, stream>>>(wkc, wkcT, 128, 512, 65536, 65536);
  gemm_bt<true><<<dim3(T_SEQ / 128, 512 / 128, NH), 256, 0, stream>>>(
      qbuf, wkcT, q_inp, 512, 128, NH * QKD, 128, 576, QKD, 65536, (long)T_SEQ * 576);
  rope_q<<<(T_SEQ * NH * 32) / 256, 256, 0, stream>>>(qbuf, q_inp);
  flash_attn<<<dim3(NH, 32), 256, 0, stream>>>(q_inp, k_inp, v_t, q_inp);
  transpose_f2b<<<dim3(128 / 32, 512 / 32, NH), tb, 0, stream>>>(wvc, wvcT, 512, 128, 65536, 65536);
  gemm_bt<true><<<dim3(T_SEQ / 128, 1, NH), 256, 0, stream>>>(
      q_inp, wvcT, attn, 128, 512, 576, 512, NH * VDIM, (long)T_SEQ * 576, 65536, 128);
  transpose_f2b<<<dim3(HID / 32, (NH * VDIM) / 32, 1), tb, 0, stream>>>(wo, woT, NH * VDIM, HID, 0, 0);
  gemm_bt<false><<<dim3(T_SEQ / 128, HID / 128, 1), 256, 0, stream>>>(
      attn, woT, out, HID, NH * VDIM, NH * VDIM, NH * VDIM, HID, 0, 0, 0);
}

// Round 6
// 944.946 us; speedup vs baseline: 1.8275x; 1.8275x over previous
//
#include <hip/hip_runtime.h>

#define T_SEQ 2048
#define HID   5120
#define QLR   1536
#define KVLR  512
#define NOPE  128
#define ROPE_D 64
#define VDIM  128
#define NH    32
#define QKD   192

constexpr float SCALE   = 0.07216878364870323f; // 192^-0.5
constexpr float EPS_F   = 1e-6f;
constexpr float LN10000 = 9.210340371976184f;

typedef __bf16 bf16x8 __attribute__((ext_vector_type(8)));
typedef float  f32x4  __attribute__((ext_vector_type(4)));

__device__ __forceinline__ unsigned short f2bf(float f) {
  union { float f; unsigned u; } v; v.f = f;
  unsigned u = v.u + 0x7fffu + ((v.u >> 16) & 1u);
  return (unsigned short)(u >> 16);
}
__device__ __forceinline__ float bf2f(unsigned short b) {
  union { unsigned u; float f; } v; v.u = ((unsigned)b) << 16;
  return v.f;
}

// async global->LDS, 16B per lane; LDS dest = wave-uniform base + lane*16
__device__ __forceinline__ void glds16(const unsigned short* g, unsigned short* l) {
  __builtin_amdgcn_global_load_lds((const __attribute__((address_space(1))) void*)g,
                                   (__attribute__((address_space(3))) void*)l, 16, 0, 0);
}

// ---------------- elementwise f32 -> bf16 ----------------
__global__ void conv_f2b(const float* __restrict__ in, unsigned short* __restrict__ out, long n) {
  long i = ((long)blockIdx.x * blockDim.x + threadIdx.x) * 4;
  if (i >= n) return;
  float4 v = *(const float4*)(in + i);
  uint2 o;
  o.x = (unsigned)f2bf(v.x) | ((unsigned)f2bf(v.y) << 16);
  o.y = (unsigned)f2bf(v.z) | ((unsigned)f2bf(v.w) << 16);
  *(uint2*)(out + i) = o;
}

// ---------------- transpose f32 (RxC) -> bf16 (CxR), batched ----------------
__global__ void transpose_f2b(const float* __restrict__ in, unsigned short* __restrict__ out,
                              int R, int C, long inB, long outB) {
  __shared__ float tile[32][33];
  const float* inp = in + (long)blockIdx.z * inB;
  unsigned short* outp = out + (long)blockIdx.z * outB;
  int c0 = blockIdx.x * 32, r0 = blockIdx.y * 32;
  int x = threadIdx.x, y = threadIdx.y; // (32,8)
#pragma unroll
  for (int yy = 0; yy < 32; yy += 8)
    tile[y + yy][x] = inp[(long)(r0 + y + yy) * C + c0 + x];
  __syncthreads();
#pragma unroll
  for (int yy = 0; yy < 32; yy += 8)
    outp[(long)(c0 + y + yy) * R + r0 + x] = f2bf(tile[x][y + yy]);
}

// ---------------- rmsnorm rows (f32 in, bf16 out) ----------------
__global__ void rmsnorm_rows(const float* __restrict__ in, const float* __restrict__ w,
                             unsigned short* __restrict__ out, int C) {
  int t = blockIdx.x, tid = threadIdx.x;
  __shared__ float sred[4];
  const float* row = in + (long)t * C;
  float ss = 0.f;
  for (int i = tid; i < C; i += 256) { float v = row[i]; ss += v * v; }
#pragma unroll
  for (int o = 32; o; o >>= 1) ss += __shfl_xor(ss, o);
  if ((tid & 63) == 0) sred[tid >> 6] = ss;
  __syncthreads();
  ss = sred[0] + sred[1] + sred[2] + sred[3];
  float rinv = rsqrtf(ss / (float)C + EPS_F);
  for (int i = tid; i < C; i += 256)
    out[(long)t * C + i] = f2bf(row[i] * rinv * w[i]);
}

// ---------------- kv latent: rmsnorm(512)->k_input & v_t; rope on k_pe ----------------
__global__ void norm_rope_k(const float* __restrict__ latent, const float* __restrict__ w,
                            unsigned short* __restrict__ k_input, unsigned short* __restrict__ v_t) {
  int t = blockIdx.x, tid = threadIdx.x;
  __shared__ float sred[4];
  const float* row = latent + (long)t * 576;
  float ss = 0.f;
  for (int i = tid; i < 512; i += 256) { float v = row[i]; ss += v * v; }
#pragma unroll
  for (int o = 32; o; o >>= 1) ss += __shfl_xor(ss, o);
  if ((tid & 63) == 0) sred[tid >> 6] = ss;
  __syncthreads();
  ss = sred[0] + sred[1] + sred[2] + sred[3];
  float rinv = rsqrtf(ss * (1.f / 512.f) + EPS_F);
  for (int i = tid; i < 512; i += 256) {
    unsigned short b = f2bf(row[i] * rinv * w[i]);
    k_input[(long)t * 576 + i] = b;
    v_t[(long)i * T_SEQ + t] = b;  // V^T for PV MFMA B-frags
  }
  if (tid < 32) {
    float fr = (float)t * expf(-((float)(2 * tid) / 64.f) * LN10000);
    float c = cosf(fr), s = sinf(fr);
    float x1 = row[512 + 2 * tid], x2 = row[512 + 2 * tid + 1];
    k_input[(long)t * 576 + 512 + 2 * tid]     = f2bf(x1 * c - x2 * s);
    k_input[(long)t * 576 + 512 + 2 * tid + 1] = f2bf(x2 * c + x1 * s);
  }
}

// ---------------- rope on q_pe: q (T, H*192) -> q_input[h][t][512..576] ----------------
__global__ void rope_q(const unsigned short* __restrict__ q, unsigned short* __restrict__ q_input) {
  int idx = blockIdx.x * 256 + threadIdx.x; // t*NH*32 + h*32 + i
  int i = idx & 31, h = (idx >> 5) & 31, t = idx >> 10;
  float fr = (float)t * expf(-((float)(2 * i) / 64.f) * LN10000);
  float c = cosf(fr), s = sinf(fr);
  const unsigned short* qp = q + (long)t * (NH * QKD) + h * QKD + NOPE + 2 * i;
  float x1 = bf2f(qp[0]), x2 = bf2f(qp[1]);
  unsigned short* op = q_input + ((long)h * T_SEQ + t) * 576 + 512 + 2 * i;
  op[0] = f2bf(x1 * c - x2 * s);
  op[1] = f2bf(x2 * c + x1 * s);
}

// ---------------- GEMM: C[M,N] = A[M,K] @ Bt[N,K]^T (bf16 in, f32 acc) ----------------
template <bool OUT_BF16>
__global__ __launch_bounds__(256, 2)
void gemm_bt(const unsigned short* __restrict__ A, const unsigned short* __restrict__ Bt,
             void* __restrict__ Cv, int N, int K,
             long lda, long ldb, long ldc, long bA, long bB, long bC) {
  __shared__ __align__(16) unsigned short sA[128 * 64];
  __shared__ __align__(16) unsigned short sB[128 * 64];
  const int b = blockIdx.z;
  const unsigned short* Ap = A + (long)b * bA;
  const unsigned short* Bp = Bt + (long)b * bB;
  const int m0 = blockIdx.x * 128, n0 = blockIdx.y * 128;
  const int tid = threadIdx.x, lane = tid & 63, w = tid >> 6;
  const int wr = w >> 1, wc = w & 1, lo = lane & 15, hi = lane >> 4;
  f32x4 acc[4][4];
#pragma unroll
  for (int i = 0; i < 4; i++)
#pragma unroll
    for (int j = 0; j < 4; j++) acc[i][j] = (f32x4){0.f, 0.f, 0.f, 0.f};
  const int r0 = tid >> 3, cc = tid & 7;
  for (int k0 = 0; k0 < K; k0 += 64) {
    __syncthreads();
#pragma unroll
    for (int i = 0; i < 4; i++) {
      glds16(Ap + (long)(m0 + i * 32 + r0) * lda + k0 + cc * 8, sA + i * 2048 + w * 512);
      glds16(Bp + (long)(n0 + i * 32 + r0) * ldb + k0 + cc * 8, sB + i * 2048 + w * 512);
    }
    __syncthreads();
#pragma unroll
    for (int s = 0; s < 2; s++) {
      bf16x8 af[4], bfr[4];
#pragma unroll
      for (int mt = 0; mt < 4; mt++)
        af[mt] = *(const bf16x8*)(sA + (wr * 64 + mt * 16 + lo) * 64 + s * 32 + hi * 8);
#pragma unroll
      for (int nt = 0; nt < 4; nt++)
        bfr[nt] = *(const bf16x8*)(sB + (wc * 64 + nt * 16 + lo) * 64 + s * 32 + hi * 8);
#pragma unroll
      for (int mt = 0; mt < 4; mt++)
#pragma unroll
        for (int nt = 0; nt < 4; nt++)
          acc[mt][nt] = __builtin_amdgcn_mfma_f32_16x16x32_bf16(af[mt], bfr[nt], acc[mt][nt], 0, 0, 0);
    }
  }
#pragma unroll
  for (int mt = 0; mt < 4; mt++)
#pragma unroll
    for (int nt = 0; nt < 4; nt++) {
      int col = n0 + wc * 64 + nt * 16 + lo;
      if (col < N) {
#pragma unroll
        for (int r = 0; r < 4; r++) {
          long row = m0 + wr * 64 + mt * 16 + hi * 4 + r;
          float v = acc[mt][nt][r];
          if constexpr (OUT_BF16)
            ((unsigned short*)Cv)[(long)b * bC + row * ldc + col] = f2bf(v);
          else
            ((float*)Cv)[(long)b * bC + row * ldc + col] = v;
        }
      }
    }
}

// ---------------- flash attention v9: 2-chunk slots, 8-buffer pool, launch_bounds revert ----
// v8's __launch_bounds__(256,4) capped VGPRs at 128 < ~230 live state -> full spill
// (hbm 3.8 GB scratch, 3.3x slower). Occupancy is register-bound at 2 blocks/CU; revert.
// v7's real overhead: 17 barriers/tile with only ~150 cyc compute each -> per-slot
// rendezvous+skew dominates (~900+ cyc/slot). v9 coarsens: 2 chunks per slot
// (16 MFMA + 8 ds_read per barrier), 9 slots/tile. Stage-ahead D=2 slots requires
// B=8 chunk-buffers (64 KB LDS, fits 2 blocks/CU); buffer = (kb0+ci)&7, kb0 += 1
// per tile (17 % 8). Per-wave vmcnt (2 stage-groups of <=4 loads outstanding):
// slots 0-5 WB(8); slot 6 WB(6) (stages single-chunk slot 8); slot 7 WB(6);
// slot 8 WB(8); last tile: WB(2)/WB(0). s_setprio(1) wraps MFMA clusters (T5):
// the two co-resident blocks run phase-shifted, so the computing block preempts
// the staging one. All reuse distances verified >= 3 chunks and != 0 mod 8.
__global__ __launch_bounds__(256, 2)
void flash_attn(const unsigned short* __restrict__ q_input,
                const unsigned short* __restrict__ k_input,
                const unsigned short* __restrict__ v_t,
                unsigned short* __restrict__ ctx_out) {
  __shared__ __align__(16) unsigned short sKV[8 * 64 * 64];  // 64 KB pool, 8 bufs x 8 KB
  const int h = blockIdx.x;
  const int i0 = (31 - blockIdx.y) * 64;  // biggest blocks dispatch first
  const int tid = threadIdx.x;
  const int lane = tid & 63, w = tid >> 6;
  const int lo = lane & 15, hi = lane >> 4;
  const int qrow = i0 + w * 16 + lo;

  bf16x8 qf[18];
  {
    const unsigned short* qr = q_input + ((long)h * T_SEQ + qrow) * 576;
#pragma unroll
    for (int i = 0; i < 18; i++) qf[i] = *(const bf16x8*)(qr + i * 32 + hi * 8);
  }
  // settle qf loads HERE (one vmcnt wait outside the loop) so no qf-related
  // vmcnt waits appear inside the pipeline.
#pragma unroll
  for (int i = 0; i < 18; i++) asm volatile("" : "+v"(qf[i]));

  float l_r = 0.f;
  f32x4 of[32];
#pragma unroll
  for (int o = 0; o < 32; o++) of[o] = (f32x4){0.f, 0.f, 0.f, 0.f};

  // staging lane constants (element offsets). Chunk = 64 rows x 64 cols bf16;
  // 16B-unit u = w*128 + i*64 + lane; row = u>>3, slot = (u ^ (u>>3)) & 7.
  int kOff[2], vOff[2];
#pragma unroll
  for (int i = 0; i < 2; i++) {
    int u = w * 128 + i * 64 + lane;
    int sl = (u ^ (u >> 3)) & 7;        // inverse-swizzled source slot
    kOff[i] = (u >> 3) * 576 + sl * 8;  // K: row = key (stride 576)
    vOff[i] = (u >> 3) * T_SEQ + sl * 8;// V^T: row = vd (stride T_SEQ)
  }
  // read-side swizzle: 16B-group ((ks*4+hi)^(lo&7)), in elements
  const int sw[2] = { ((0 + hi) ^ (lo & 7)) * 8, ((4 + hi) ^ (lo & 7)) * 8 };
  int kb0 = 0;  // buffer index of this tile's chunk 0 (uniform, SGPR)

#define BUF(ci) ((kb0 + (ci)) & 7)
#define STAGE_K(c, ci, base)                                                  \
  {                                                                           \
    unsigned short* d_ = sKV + BUF(ci) * 4096 + w * 1024;                     \
    _Pragma("unroll")                                                         \
    for (int i_ = 0; i_ < 2; i_++)                                            \
      glds16(k_input + (base) + kOff[i_] + (c) * 64, d_ + i_ * 512);          \
  }
#define STAGE_V(ch, jk)                                                       \
  {                                                                           \
    unsigned short* d_ = sKV + BUF(9 + (ch)) * 4096 + w * 1024;               \
    _Pragma("unroll")                                                         \
    for (int i_ = 0; i_ < 2; i_++)                                            \
      glds16(v_t + (long)(ch) * 64 * T_SEQ + vOff[i_] + (jk), d_ + i_ * 512); \
  }
#define WB(N)                                                                 \
  __builtin_amdgcn_sched_barrier(0);                                          \
  asm volatile("s_waitcnt vmcnt(" #N ")" ::: "memory");                       \
  __builtin_amdgcn_s_barrier();                                               \
  __builtin_amdgcn_sched_barrier(0);
#define SP1 __builtin_amdgcn_s_setprio(1);
#define SP0 __builtin_amdgcn_s_setprio(0);
#define COMPUTE_K(c)                                                          \
  {                                                                           \
    const unsigned short* kb_ = sKV + BUF(c) * 4096 + lo * 64;                \
    _Pragma("unroll")                                                         \
    for (int ks_ = 0; ks_ < 2; ks_++)                                         \
      _Pragma("unroll")                                                       \
      for (int nt_ = 0; nt_ < 4; nt_++) {                                     \
        bf16x8 a_ = *(const bf16x8*)(kb_ + nt_ * 1024 + sw[ks_]);             \
        sacc[nt_] = __builtin_amdgcn_mfma_f32_16x16x32_bf16(                  \
            a_, qf[2 * (c) + ks_], sacc[nt_], 0, 0, 0);                       \
      }                                                                       \
  }
#define COMPUTE_V(ch)                                                         \
  {                                                                           \
    const unsigned short* vb_ = sKV + BUF(9 + (ch)) * 4096 + lo * 64;         \
    _Pragma("unroll")                                                         \
    for (int kk_ = 0; kk_ < 2; kk_++)                                         \
      _Pragma("unroll")                                                       \
      for (int ot_ = 0; ot_ < 4; ot_++) {                                     \
        bf16x8 b_ = *(const bf16x8*)(vb_ + ot_ * 1024 + sw[kk_]);             \
        of[(ch) * 4 + ot_] = __builtin_amdgcn_mfma_f32_16x16x32_bf16(         \
            pa[kk_], b_, of[(ch) * 4 + ot_], 0, 0, 0);                        \
      }                                                                       \
  }

  // prologue: chunks 0..3 (K0..K3) of first tile -> 8 loads/wave outstanding
  STAGE_K(0, 0, 0); STAGE_K(1, 1, 0);
  STAGE_K(2, 2, 0); STAGE_K(3, 3, 0);

  for (int j0 = 0; j0 <= i0; j0 += 64) {
    const long kcur = (long)j0 * 576;
    const long knxt = kcur + 64 * 576;
    const bool more = (j0 < i0);
    f32x4 sacc[4];
#pragma unroll
    for (int nt = 0; nt < 4; nt++) sacc[nt] = (f32x4){0.f, 0.f, 0.f, 0.f};

    // slot0: stage K4,K5; compute K0,K1
    STAGE_K(4, 4, kcur); STAGE_K(5, 5, kcur); WB(8);
    SP1 COMPUTE_K(0); COMPUTE_K(1); SP0
    // slot1: stage K6,K7; compute K2,K3
    STAGE_K(6, 6, kcur); STAGE_K(7, 7, kcur); WB(8);
    SP1 COMPUTE_K(2); COMPUTE_K(3); SP0
    // slot2: stage K8,V0; compute K4,K5
    STAGE_K(8, 8, kcur); STAGE_V(0, j0); WB(8);
    SP1 COMPUTE_K(4); COMPUTE_K(5); SP0
    // slot3: stage V1,V2; compute K6,K7
    STAGE_V(1, j0); STAGE_V(2, j0); WB(8);
    SP1 COMPUTE_K(6); COMPUTE_K(7); SP0
    // slot4: stage V3,V4; compute K8 + softmax + V0
    STAGE_V(3, j0); STAGE_V(4, j0); WB(8);
    SP1 COMPUTE_K(8); SP0

    // ---- softmax (no max-tracking; stats are per-lane) ----
    const bool diag = (j0 == i0);
    int D2[4][2];
    float psum = 0.f;
#pragma unroll
    for (int nt = 0; nt < 4; nt++) {
      float pv[4];
#pragma unroll
      for (int r = 0; r < 4; r++) {
        float e = __expf(sacc[nt][r] * SCALE);
        if (diag && (j0 + nt * 16 + hi * 4 + r) > qrow) e = 0.f;
        pv[r] = e;
        psum += e;
      }
      D2[nt][0] = (int)f2bf(pv[0]) | ((int)f2bf(pv[1]) << 16);
      D2[nt][1] = (int)f2bf(pv[2]) | ((int)f2bf(pv[3]) << 16);
    }
    psum += __shfl_xor(psum, 16);
    psum += __shfl_xor(psum, 32);
    l_r += psum;
    // ---- P -> PV A-frags in-register (two bpermute rounds + select) ----
    bf16x8 pa[2];
    {
      const int s0 = lo + 32 * (hi & 1);
#pragma unroll
      for (int kk = 0; kk < 2; kk++) {
        int d[4];
#pragma unroll
        for (int dd = 0; dd < 2; dd++) {
          int t0 = __shfl(D2[2 * kk][dd], s0);
          int t1 = __shfl(D2[2 * kk + 1][dd], s0);
          d[dd] = (hi >> 1) ? t1 : t0;
          int t2 = __shfl(D2[2 * kk][dd], s0 + 16);
          int t3 = __shfl(D2[2 * kk + 1][dd], s0 + 16);
          d[2 + dd] = (hi >> 1) ? t3 : t2;
        }
        int4 di = {d[0], d[1], d[2], d[3]};
        pa[kk] = *(bf16x8*)&di;
      }
    }
    SP1 COMPUTE_V(0); SP0
    // slot5: stage V5,V6; compute V1,V2
    STAGE_V(5, j0); STAGE_V(6, j0); WB(8);
    SP1 COMPUTE_V(1); COMPUTE_V(2); SP0
    // slot6: stage V7 (single); compute V3,V4
    STAGE_V(7, j0); WB(6);
    SP1 COMPUTE_V(3); COMPUTE_V(4); SP0
    // slot7: stage next-tile K0,K1; compute V5,V6
    if (more) { STAGE_K(0, 17, knxt); STAGE_K(1, 18, knxt); WB(6); } else { WB(2); }
    SP1 COMPUTE_V(5); COMPUTE_V(6); SP0
    // slot8: stage next-tile K2,K3; compute V7
    if (more) { STAGE_K(2, 19, knxt); STAGE_K(3, 20, knxt); WB(8); } else { WB(0); }
    SP1 COMPUTE_V(7); SP0
    kb0 = (kb0 + 1) & 7;  // 17 chunks % 8 buffers == 1
  }
#undef BUF
#undef STAGE_K
#undef STAGE_V
#undef WB
#undef SP1
#undef SP0
#undef COMPUTE_K
#undef COMPUTE_V

  // ---- epilogue ----
  float linv[4];
#pragma unroll
  for (int r = 0; r < 4; r++) linv[r] = 1.f / __shfl(l_r, hi * 4 + r);
#pragma unroll
  for (int o = 0; o < 32; o++) {
    int vd = o * 16 + lo;
#pragma unroll
    for (int r = 0; r < 4; r++) {
      long row = (long)h * T_SEQ + i0 + w * 16 + hi * 4 + r;
      ctx_out[row * 576 + vd] = f2bf(of[o][r] * linv[r]);
    }
  }
}

// ---------------- host orchestration ----------------
extern "C" void kernel_launch(void* const* d_in, const int* in_sizes, int n_in,
                              void* d_out, int out_size, void* d_ws, size_t ws_size,
                              hipStream_t stream) {
  (void)in_sizes; (void)n_in; (void)out_size; (void)ws_size;
  const float* hs    = (const float*)d_in[0];
  const float* wqa   = (const float*)d_in[2];
  const float* qlnw  = (const float*)d_in[3];
  const float* wqb   = (const float*)d_in[4];
  const float* wkva  = (const float*)d_in[5];
  const float* kvlnw = (const float*)d_in[6];
  const float* wkc   = (const float*)d_in[7];
  const float* wvc   = (const float*)d_in[8];
  const float* wo    = (const float*)d_in[9];
  float* out = (float*)d_out;

  char* base = (char*)d_ws;
  size_t off = 0;
  auto alloc = [&](size_t bytes) {
    char* r = base + off;
    off += (bytes + 255) & ~(size_t)255;
    return r;
  };
  unsigned short* hs_b  = (unsigned short*)alloc((size_t)T_SEQ * HID * 2);
  unsigned short* wqaT  = (unsigned short*)alloc((size_t)QLR * HID * 2);
  unsigned short* wqbT  = (unsigned short*)alloc((size_t)NH * QKD * QLR * 2);
  unsigned short* wkvaT = (unsigned short*)alloc((size_t)640 * HID * 2);  // 576 padded to 640
  unsigned short* wkcT  = (unsigned short*)alloc((size_t)NH * 512 * 128 * 2);
  unsigned short* wvcT  = (unsigned short*)alloc((size_t)NH * 128 * 512 * 2);
  float*          q_a   = (float*)alloc((size_t)T_SEQ * QLR * 4);
  unsigned short* q_a_n = (unsigned short*)alloc((size_t)T_SEQ * QLR * 2);
  unsigned short* qbuf  = (unsigned short*)alloc((size_t)T_SEQ * NH * QKD * 2);
  float*          latent= (float*)alloc((size_t)T_SEQ * 576 * 4);
  unsigned short* k_inp = (unsigned short*)alloc((size_t)T_SEQ * 576 * 2);
  unsigned short* v_t   = (unsigned short*)alloc((size_t)512 * T_SEQ * 2);
  unsigned short* q_inp = (unsigned short*)alloc((size_t)NH * T_SEQ * 576 * 2);
  unsigned short* woT   = (unsigned short*)base;  // over hs_b+wqaT+wqbT (dead by then)
  unsigned short* attn  = qbuf;                   // over qbuf (dead by then)

  dim3 tb(32, 8);
  conv_f2b<<<(T_SEQ * HID) / 1024, 256, 0, stream>>>(hs, hs_b, (long)T_SEQ * HID);
  transpose_f2b<<<dim3(QLR / 32, HID / 32, 1), tb, 0, stream>>>(wqa, wqaT, HID, QLR, 0, 0);
  transpose_f2b<<<dim3(576 / 32, HID / 32, 1), tb, 0, stream>>>(wkva, wkvaT, HID, 576, 0, 0);
  gemm_bt<false><<<dim3(T_SEQ / 128, QLR / 128, 1), 256, 0, stream>>>(
      hs_b, wqaT, q_a, QLR, HID, HID, HID, QLR, 0, 0, 0);
  gemm_bt<false><<<dim3(T_SEQ / 128, 5, 1), 256, 0, stream>>>(
      hs_b, wkvaT, latent, 576, HID, HID, HID, 576, 0, 0, 0);
  rmsnorm_rows<<<T_SEQ, 256, 0, stream>>>(q_a, qlnw, q_a_n, QLR);
  norm_rope_k<<<T_SEQ, 256, 0, stream>>>(latent, kvlnw, k_inp, v_t);
  transpose_f2b<<<dim3((NH * QKD) / 32, QLR / 32, 1), tb, 0, stream>>>(wqb, wqbT, QLR, NH * QKD, 0, 0);
  gemm_bt<true><<<dim3(T_SEQ / 128, (NH * QKD) / 128, 1), 256, 0, stream>>>(
      q_a_n, wqbT, qbuf, NH * QKD, QLR, QLR, QLR, NH * QKD, 0, 0, 0);
  transpose_f2b<<<dim3(512 / 32, 128 / 32, NH), tb, 0, stream>>>(wkc, wkcT, 128, 512, 65536, 65536);
  gemm_bt<true><<<dim3(T_SEQ / 128, 512 / 128, NH), 256, 0, stream>>>(
      qbuf, wkcT, q_inp, 512, 128, NH * QKD, 128, 576, QKD, 65536, (long)T_SEQ * 576);
  rope_q<<<(T_SEQ * NH * 32) / 256, 256, 0, stream>>>(qbuf, q_inp);
  flash_attn<<<dim3(NH, 32), 256, 0, stream>>>(q_inp, k_inp, v_t, q_inp);
  transpose_f2b<<<dim3(128 / 32, 512 / 32, NH), tb, 0, stream>>>(wvc, wvcT, 512, 128, 65536, 65536);
  gemm_bt<true><<<dim3(T_SEQ / 128, 1, NH), 256, 0, stream>>>(
      q_inp, wvcT, attn, 128, 512, 576, 512, NH * VDIM, (long)T_SEQ * 576, 65536, 128);
  transpose_f2b<<<dim3(HID / 32, (NH * VDIM) / 32, 1), tb, 0, stream>>>(wo, woT, NH * VDIM, HID, 0, 0);
  gemm_bt<false><<<dim3(T_SEQ / 128, HID / 128, 1), 256, 0, stream>>>(
      attn, woT, out, HID, NH * VDIM, NH * VDIM, NH * VDIM, HID, 0, 0, 0);
}